// Round 1
// baseline (418.770 us; speedup 1.0000x reference)
//
#include <hip/hip_runtime.h>

#define V_N 4096
#define C_N 32
#define T_N 512

// ---------------------------------------------------------------------------
// rhsT[v][t] = sum_c x[v,c,t] * U3[c]
__global__ __launch_bounds__(256) void k_rhs(const float* __restrict__ x,
                                             const float* __restrict__ U3,
                                             float* __restrict__ rhsT) {
    int v = blockIdx.x;
    int t = threadIdx.x;
    const float* xp = x + (size_t)v * (C_N * T_N);
    float a0 = 0.f, a1 = 0.f;
#pragma unroll
    for (int c = 0; c < C_N; ++c) {
        float u = U3[c];
        a0 = fmaf(xp[c * T_N + t], u, a0);
        a1 = fmaf(xp[c * T_N + t + 256], u, a1);
    }
    rhsT[(size_t)v * T_N + t] = a0;
    rhsT[(size_t)v * T_N + t + 256] = a1;
}

// ---------------------------------------------------------------------------
// tmpT[c][t] += sum_{v in chunk} x[v,c,t] * U1[v]   (atomic across 64 chunks)
__global__ __launch_bounds__(256) void k_tmp(const float* __restrict__ x,
                                             const float* __restrict__ U1,
                                             float* __restrict__ tmpT) {
    int chunk = blockIdx.x;   // 64 chunks of 64 v
    int c = blockIdx.y;
    int t = threadIdx.x;
    float a0 = 0.f, a1 = 0.f;
    int v0 = chunk * 64;
    for (int v = v0; v < v0 + 64; ++v) {
        float u = U1[v];
        const float* xp = x + (size_t)v * (C_N * T_N) + c * T_N;
        a0 = fmaf(xp[t], u, a0);
        a1 = fmaf(xp[t + 256], u, a1);
    }
    atomicAdd(&tmpT[c * T_N + t], a0);
    atomicAdd(&tmpT[c * T_N + t + 256], a1);
}

// ---------------------------------------------------------------------------
// lhs[t][v2] = sum_c tmpT[c][t] * U2[c][v2]
__global__ __launch_bounds__(256) void k_lhs(const float* __restrict__ tmpT,
                                             const float* __restrict__ U2,
                                             float* __restrict__ lhs) {
    int t = blockIdx.y;
    int v2 = blockIdx.x * 256 + threadIdx.x;
    float a = 0.f;
#pragma unroll
    for (int c = 0; c < C_N; ++c)
        a = fmaf(tmpT[c * T_N + t], U2[(size_t)c * V_N + v2], a);
    lhs[(size_t)t * V_N + v2] = a;
}

// ---------------------------------------------------------------------------
// VeT[s][t] = Ve[t][s]
__global__ void k_vt(const float* __restrict__ Ve, float* __restrict__ VeT) {
    __shared__ float tile[32][33];
    int bx = blockIdx.x * 32, by = blockIdx.y * 32;
    int tx = threadIdx.x, ty = threadIdx.y;  // 32 x 8
#pragma unroll
    for (int i = 0; i < 32; i += 8)
        tile[ty + i][tx] = Ve[(size_t)(by + ty + i) * T_N + bx + tx];
    __syncthreads();
#pragma unroll
    for (int i = 0; i < 32; i += 8)
        VeT[(size_t)(bx + ty + i) * T_N + by + tx] = tile[tx][ty + i];
}

// ---------------------------------------------------------------------------
// P[s][r] += sum_{v in kslice} rhsT[v][s] * lhs[r][v]   (atomic over 8 slices)
__global__ __launch_bounds__(256) void k_P(const float* __restrict__ rhsT,
                                           const float* __restrict__ lhs,
                                           float* __restrict__ P) {
    int rbase = blockIdx.x * 64, sbase = blockIdx.y * 64, kbase = blockIdx.z * 512;
    __shared__ float As[16][64];   // [v][s]
    __shared__ float Bs[16][65];   // [v][r] (padded)
    int tid = threadIdx.x;
    int tx = tid & 15, ty = tid >> 4;
    float acc[4][4] = {};
    for (int k0 = kbase; k0 < kbase + 512; k0 += 16) {
        for (int i = tid; i < 1024; i += 256) {
            int kk = i >> 6, ss = i & 63;
            As[kk][ss] = rhsT[(size_t)(k0 + kk) * T_N + sbase + ss];
        }
        for (int i = tid; i < 1024; i += 256) {
            int rr = i >> 4, kk = i & 15;
            Bs[kk][rr] = lhs[(size_t)(rbase + rr) * V_N + k0 + kk];
        }
        __syncthreads();
#pragma unroll
        for (int kk = 0; kk < 16; ++kk) {
            float a[4], b[4];
#pragma unroll
            for (int i = 0; i < 4; ++i) a[i] = As[kk][ty * 4 + i];
#pragma unroll
            for (int j = 0; j < 4; ++j) b[j] = Bs[kk][tx * 4 + j];
#pragma unroll
            for (int i = 0; i < 4; ++i)
#pragma unroll
                for (int j = 0; j < 4; ++j) acc[i][j] = fmaf(a[i], b[j], acc[i][j]);
        }
        __syncthreads();
    }
#pragma unroll
    for (int i = 0; i < 4; ++i)
#pragma unroll
        for (int j = 0; j < 4; ++j)
            atomicAdd(&P[(size_t)(sbase + ty * 4 + i) * T_N + rbase + tx * 4 + j],
                      acc[i][j]);
}

// ---------------------------------------------------------------------------
// E[c][t][r] = sum_s Ve[t][s] * sigmoid(P[s][r] + be[c][s][r])   (into d_out)
__global__ __launch_bounds__(256) void k_E(const float* __restrict__ VeT,
                                           const float* __restrict__ P,
                                           const float* __restrict__ be,
                                           float* __restrict__ E) {
    int rbase = blockIdx.x * 64, tbase = blockIdx.y * 64, c = blockIdx.z;
    __shared__ float As[16][64];  // [s][t]
    __shared__ float Bs[16][64];  // [s][r]
    int tid = threadIdx.x;
    int tx = tid & 15, ty = tid >> 4;
    const size_t cTT = (size_t)c * T_N * T_N;
    float acc[4][4] = {};
    for (int k0 = 0; k0 < T_N; k0 += 16) {
        for (int i = tid; i < 1024; i += 256) {
            int kk = i >> 6, tt = i & 63;
            As[kk][tt] = VeT[(size_t)(k0 + kk) * T_N + tbase + tt];
            size_t off = (size_t)(k0 + kk) * T_N + rbase + tt;
            float xv = P[off] + be[cTT + off];
            Bs[kk][tt] = 1.f / (1.f + __expf(-xv));
        }
        __syncthreads();
#pragma unroll
        for (int kk = 0; kk < 16; ++kk) {
            float a[4], b[4];
#pragma unroll
            for (int i = 0; i < 4; ++i) a[i] = As[kk][ty * 4 + i];
#pragma unroll
            for (int j = 0; j < 4; ++j) b[j] = Bs[kk][tx * 4 + j];
#pragma unroll
            for (int i = 0; i < 4; ++i)
#pragma unroll
                for (int j = 0; j < 4; ++j) acc[i][j] = fmaf(a[i], b[j], acc[i][j]);
        }
        __syncthreads();
    }
#pragma unroll
    for (int i = 0; i < 4; ++i) {
        float4 vv = make_float4(acc[i][0], acc[i][1], acc[i][2], acc[i][3]);
        *(float4*)&E[cTT + (size_t)(tbase + ty * 4 + i) * T_N + rbase + tx * 4] = vv;
    }
}

// ---------------------------------------------------------------------------
// partial (max, sumexp) over t-chunks of 64 for each (c, r)
__global__ __launch_bounds__(256) void k_ml(const float* __restrict__ E,
                                            float* __restrict__ mpart,
                                            float* __restrict__ lpart) {
    int r = blockIdx.x * 256 + threadIdx.x;
    int tc = blockIdx.y, c = blockIdx.z;
    const float* col = E + (size_t)c * T_N * T_N + r;
    float m = -1e30f, l = 0.f;
    for (int t = tc * 64; t < tc * 64 + 64; ++t) {
        float v = col[(size_t)t * T_N];
        float mn = fmaxf(m, v);
        l = l * __expf(m - mn) + __expf(v - mn);
        m = mn;
    }
    mpart[(size_t)(tc * C_N + c) * T_N + r] = m;
    lpart[(size_t)(tc * C_N + c) * T_N + r] = l;
}

// ---------------------------------------------------------------------------
// combine partials (redundantly per t-chunk) and normalize in place
__global__ __launch_bounds__(256) void k_norm(float* __restrict__ E,
                                              const float* __restrict__ mpart,
                                              const float* __restrict__ lpart) {
    int r = blockIdx.x * 256 + threadIdx.x;
    int tc = blockIdx.y, c = blockIdx.z;
    float m = -1e30f, l = 0.f;
#pragma unroll
    for (int i = 0; i < 8; ++i) {
        float mi = mpart[(size_t)(i * C_N + c) * T_N + r];
        float li = lpart[(size_t)(i * C_N + c) * T_N + r];
        float mn = fmaxf(m, mi);
        l = l * __expf(m - mn) + li * __expf(mi - mn);
        m = mn;
    }
    float inv = 1.f / l;
    float* col = E + (size_t)c * T_N * T_N + r;
    for (int t = tc * 64; t < tc * 64 + 64; ++t) {
        col[(size_t)t * T_N] = __expf(col[(size_t)t * T_N] - m) * inv;
    }
}

// ---------------------------------------------------------------------------
extern "C" void kernel_launch(void* const* d_in, const int* in_sizes, int n_in,
                              void* d_out, int out_size, void* d_ws, size_t ws_size,
                              hipStream_t stream) {
    const float* x  = (const float*)d_in[0];
    const float* U1 = (const float*)d_in[1];
    const float* U2 = (const float*)d_in[2];
    const float* U3 = (const float*)d_in[3];
    const float* be = (const float*)d_in[4];
    const float* Ve = (const float*)d_in[5];
    float* out = (float*)d_out;

    float* ws    = (float*)d_ws;
    float* rhsT  = ws;                // 4096*512      = 2097152
    float* lhs   = ws + 2097152;      // 512*4096      = 2097152
    float* tmpT  = ws + 4194304;      // 32*512        = 16384
    float* P     = ws + 4210688;      // 512*512       = 262144
    float* VeT   = ws + 4472832;      // 512*512       = 262144
    float* mpart = ws + 4734976;      // 8*32*512      = 131072
    float* lpart = ws + 4866048;      // 8*32*512      = 131072
    // total 4997120 floats ~= 20 MB

    hipMemsetAsync(tmpT, 0, 16384 * sizeof(float), stream);
    hipMemsetAsync(P, 0, 262144 * sizeof(float), stream);

    k_rhs<<<V_N, 256, 0, stream>>>(x, U3, rhsT);
    k_tmp<<<dim3(64, C_N), 256, 0, stream>>>(x, U1, tmpT);
    k_lhs<<<dim3(V_N / 256, T_N), 256, 0, stream>>>(tmpT, U2, lhs);
    k_vt<<<dim3(16, 16), dim3(32, 8), 0, stream>>>(Ve, VeT);
    k_P<<<dim3(8, 8, 8), 256, 0, stream>>>(rhsT, lhs, P);
    k_E<<<dim3(8, 8, C_N), 256, 0, stream>>>(VeT, P, be, out);
    k_ml<<<dim3(2, 8, C_N), 256, 0, stream>>>(out, mpart, lpart);
    k_norm<<<dim3(2, 8, C_N), 256, 0, stream>>>(out, mpart, lpart);
}

// Round 2
// 280.926 us; speedup vs baseline: 1.4907x; 1.4907x over previous
//
#include <hip/hip_runtime.h>

#define V_N 4096
#define C_N 32
#define T_N 512

typedef float f32x4 __attribute__((ext_vector_type(4)));
typedef __bf16 bf16x8 __attribute__((ext_vector_type(8)));

// ---------------------------------------------------------------------------
// Fused first pass over x (read x exactly once):
//   rhsT[v][t] = sum_c x[v,c,t]*U3[c]
//   part[chunk][c][t] = sum_{v in chunk} x[v,c,t]*U1[v]   (reduced by k_red)
__global__ __launch_bounds__(256) void k_rt(const float* __restrict__ x,
                                            const float* __restrict__ U1,
                                            const float* __restrict__ U3,
                                            float* __restrict__ rhsT,
                                            float* __restrict__ part) {
    int chunk = blockIdx.x;                 // 0..127, 32 v each
    int t = blockIdx.y * 256 + threadIdx.x; // 0..511
    float u3r[C_N];
#pragma unroll
    for (int c = 0; c < C_N; ++c) u3r[c] = U3[c];
    float accT[C_N];
#pragma unroll
    for (int c = 0; c < C_N; ++c) accT[c] = 0.f;
    int v0 = chunk * 32;
    for (int v = v0; v < v0 + 32; ++v) {
        float u1 = U1[v];
        const float* xp = x + (size_t)v * (C_N * T_N) + t;
        float u3acc = 0.f;
#pragma unroll
        for (int c = 0; c < C_N; ++c) {
            float xv = xp[c * T_N];
            u3acc = fmaf(xv, u3r[c], u3acc);
            accT[c] = fmaf(xv, u1, accT[c]);
        }
        rhsT[(size_t)v * T_N + t] = u3acc;
    }
#pragma unroll
    for (int c = 0; c < C_N; ++c)
        part[((size_t)chunk * C_N + c) * T_N + t] = accT[c];
}

// ---------------------------------------------------------------------------
// tmpT[c][t] = sum_chunk part[chunk][c][t]
__global__ __launch_bounds__(512) void k_red(const float* __restrict__ part,
                                             float* __restrict__ tmpT) {
    int c = blockIdx.x;
    int t = threadIdx.x;
    float s = 0.f;
    for (int b = 0; b < 128; ++b)
        s += part[((size_t)b * C_N + c) * T_N + t];
    tmpT[c * T_N + t] = s;
}

// ---------------------------------------------------------------------------
// Ve -> hi/lo bf16 split (hi + lo reproduces Ve to ~16 mantissa bits)
__global__ __launch_bounds__(256) void k_prep(const float* __restrict__ Ve,
                                              __bf16* __restrict__ VeHi,
                                              __bf16* __restrict__ VeLo) {
    int i = blockIdx.x * 256 + threadIdx.x;
    float v = Ve[i];
    __bf16 h = (__bf16)v;
    VeHi[i] = h;
    VeLo[i] = (__bf16)(v - (float)h);
}

// ---------------------------------------------------------------------------
// lhs[t][v2] = sum_c tmpT[c][t] * U2[c][v2]
__global__ __launch_bounds__(256) void k_lhs(const float* __restrict__ tmpT,
                                             const float* __restrict__ U2,
                                             float* __restrict__ lhs) {
    int t = blockIdx.y;
    int v2 = blockIdx.x * 256 + threadIdx.x;
    float a = 0.f;
#pragma unroll
    for (int c = 0; c < C_N; ++c)
        a = fmaf(tmpT[c * T_N + t], U2[(size_t)c * V_N + v2], a);
    lhs[(size_t)t * V_N + v2] = a;
}

// ---------------------------------------------------------------------------
// P[s][r] += sum_{v in kslice} rhsT[v][s] * lhs[r][v]  (fp32; P ~ 1e5 so bf16
// would flip ~0.5% of sigmoids -> must stay fp32)
__global__ __launch_bounds__(256) void k_P(const float* __restrict__ rhsT,
                                           const float* __restrict__ lhs,
                                           float* __restrict__ P) {
    int rbase = blockIdx.x * 64, sbase = blockIdx.y * 64, kbase = blockIdx.z * 512;
    __shared__ float As[16][64];   // [v][s]
    __shared__ float Bs[16][65];   // [v][r] (padded)
    int tid = threadIdx.x;
    int tx = tid & 15, ty = tid >> 4;
    float acc[4][4] = {};
    for (int k0 = kbase; k0 < kbase + 512; k0 += 16) {
        for (int i = tid; i < 1024; i += 256) {
            int kk = i >> 6, ss = i & 63;
            As[kk][ss] = rhsT[(size_t)(k0 + kk) * T_N + sbase + ss];
        }
        for (int i = tid; i < 1024; i += 256) {
            int rr = i >> 4, kk = i & 15;
            Bs[kk][rr] = lhs[(size_t)(rbase + rr) * V_N + k0 + kk];
        }
        __syncthreads();
#pragma unroll
        for (int kk = 0; kk < 16; ++kk) {
            float a[4], b[4];
#pragma unroll
            for (int i = 0; i < 4; ++i) a[i] = As[kk][ty * 4 + i];
#pragma unroll
            for (int j = 0; j < 4; ++j) b[j] = Bs[kk][tx * 4 + j];
#pragma unroll
            for (int i = 0; i < 4; ++i)
#pragma unroll
                for (int j = 0; j < 4; ++j) acc[i][j] = fmaf(a[i], b[j], acc[i][j]);
        }
        __syncthreads();
    }
#pragma unroll
    for (int i = 0; i < 4; ++i)
#pragma unroll
        for (int j = 0; j < 4; ++j)
            atomicAdd(&P[(size_t)(sbase + ty * 4 + i) * T_N + rbase + tx * 4 + j],
                      acc[i][j]);
}

// ---------------------------------------------------------------------------
// Fused: per block (c, 64-wide r tile), all t:
//   S[s][r] = sigmoid(P[s][r] + be[c][s][r])   (bf16, LDS, XOR-swizzled)
//   E[t][r] = sum_s (VeHi+VeLo)[t][s] * S[s][r]  via MFMA 16x16x32 bf16
//   out[c][t][r] = softmax_t(E)
// 8 waves: wave grid 4(t) x 2(r); per wave 128t x 32r = 8x2 MFMA tiles.
__global__ __launch_bounds__(512) void k_fused(const float* __restrict__ P,
                                               const float* __restrict__ be,
                                               const __bf16* __restrict__ VeHi,
                                               const __bf16* __restrict__ VeLo,
                                               float* __restrict__ out) {
    __shared__ __bf16 S[64][512];   // 64KB: S^T layout [r][s], swizzled
    const int rbase = blockIdx.x * 64;
    const int c = blockIdx.y;
    const int tid = threadIdx.x;
    const size_t cTT = (size_t)c * T_N * T_N;

    // ---- phase 1: sigmoid once per element, store S^T[r][s] bf16 swizzled
    {
        int rl = tid & 63;          // local r (column of GEMM)
        int s0 = tid >> 6;          // 0..7
        int rg = rbase + rl;
        int swz = (rl & 7) << 3;
        for (int i = 0; i < 64; ++i) {
            int s = i * 8 + s0;
            size_t off = (size_t)s * T_N + rg;
            float v = P[off] + be[cTT + off];
            float sg = 1.0f / (1.0f + __expf(-v));
            S[rl][s ^ swz] = (__bf16)sg;
        }
    }
    __syncthreads();

    const int lane = tid & 63;
    const int w = tid >> 6;     // 0..7
    const int wt = w & 3;       // t-wave: 128 rows each
    const int wr = w >> 2;      // r-wave: 32 cols each
    const int lhi = lane >> 4;  // 0..3
    const int llo = lane & 15;

    f32x4 acc[8][2];
#pragma unroll
    for (int mi = 0; mi < 8; ++mi)
#pragma unroll
        for (int ni = 0; ni < 2; ++ni) acc[mi][ni] = (f32x4)0.f;

    // ---- phase 2: K loop (s), A = Ve hi/lo from global (L2-hot), B from LDS
    for (int k0 = 0; k0 < T_N; k0 += 32) {
        bf16x8 b[2];
        int g = (k0 >> 3) + lhi;
#pragma unroll
        for (int ni = 0; ni < 2; ++ni) {
            int rr = wr * 32 + ni * 16 + llo;
            b[ni] = *(const bf16x8*)&S[rr][(g ^ (rr & 7)) << 3];
        }
#pragma unroll
        for (int mi = 0; mi < 8; ++mi) {
            int t = wt * 128 + mi * 16 + llo;
            const __bf16* pa = VeHi + (size_t)t * T_N + k0 + lhi * 8;
            const __bf16* pl = VeLo + (size_t)t * T_N + k0 + lhi * 8;
            bf16x8 ah = *(const bf16x8*)pa;
            bf16x8 al = *(const bf16x8*)pl;
#pragma unroll
            for (int ni = 0; ni < 2; ++ni) {
                acc[mi][ni] = __builtin_amdgcn_mfma_f32_16x16x32_bf16(ah, b[ni], acc[mi][ni], 0, 0, 0);
                acc[mi][ni] = __builtin_amdgcn_mfma_f32_16x16x32_bf16(al, b[ni], acc[mi][ni], 0, 0, 0);
            }
        }
    }
    __syncthreads();            // done with S; reuse as reduction buffers

    float* red = (float*)&S[0][0];  // [0..255]=max, [256..511]=sum
    float gmax[2], gsum[2];

    // ---- phase 3a: column max over t (acc row = lhi*4+q, col = llo)
#pragma unroll
    for (int ni = 0; ni < 2; ++ni) {
        float m = -3.4e38f;
#pragma unroll
        for (int mi = 0; mi < 8; ++mi)
#pragma unroll
            for (int q = 0; q < 4; ++q) m = fmaxf(m, acc[mi][ni][q]);
        m = fmaxf(m, __shfl_xor(m, 16));
        m = fmaxf(m, __shfl_xor(m, 32));
        if (lane < 16) red[wt * 64 + wr * 32 + ni * 16 + llo] = m;
    }
    __syncthreads();
#pragma unroll
    for (int ni = 0; ni < 2; ++ni) {
        int col = wr * 32 + ni * 16 + llo;
        gmax[ni] = fmaxf(fmaxf(red[col], red[64 + col]),
                         fmaxf(red[128 + col], red[192 + col]));
    }
    // ---- phase 3b: exp + column sum
#pragma unroll
    for (int ni = 0; ni < 2; ++ni) {
        float ssum = 0.f;
#pragma unroll
        for (int mi = 0; mi < 8; ++mi)
#pragma unroll
            for (int q = 0; q < 4; ++q) {
                float e = __expf(acc[mi][ni][q] - gmax[ni]);
                acc[mi][ni][q] = e;
                ssum += e;
            }
        ssum += __shfl_xor(ssum, 16);
        ssum += __shfl_xor(ssum, 32);
        if (lane < 16) red[256 + wt * 64 + wr * 32 + ni * 16 + llo] = ssum;
    }
    __syncthreads();
#pragma unroll
    for (int ni = 0; ni < 2; ++ni) {
        int col = wr * 32 + ni * 16 + llo;
        gsum[ni] = 1.0f / (red[256 + col] + red[256 + 64 + col] +
                           red[256 + 128 + col] + red[256 + 192 + col]);
    }
    // ---- phase 3c: write normalized output
#pragma unroll
    for (int mi = 0; mi < 8; ++mi)
#pragma unroll
        for (int ni = 0; ni < 2; ++ni) {
            int rg = rbase + wr * 32 + ni * 16 + llo;
#pragma unroll
            for (int q = 0; q < 4; ++q) {
                int t = wt * 128 + mi * 16 + lhi * 4 + q;
                out[cTT + (size_t)t * T_N + rg] = acc[mi][ni][q] * gsum[ni];
            }
        }
}

// ---------------------------------------------------------------------------
extern "C" void kernel_launch(void* const* d_in, const int* in_sizes, int n_in,
                              void* d_out, int out_size, void* d_ws, size_t ws_size,
                              hipStream_t stream) {
    const float* x  = (const float*)d_in[0];
    const float* U1 = (const float*)d_in[1];
    const float* U2 = (const float*)d_in[2];
    const float* U3 = (const float*)d_in[3];
    const float* be = (const float*)d_in[4];
    const float* Ve = (const float*)d_in[5];
    float* out = (float*)d_out;

    float* ws   = (float*)d_ws;
    float* rhsT = ws;                        // 2097152 floats
    float* part = ws + 2097152;              // 2097152 floats (dead after k_red)
    float* lhs  = ws + 2097152;              // overlays part (part dead by then)
    float* P    = ws + 4194304;              // 262144 floats
    __bf16* VeHi = (__bf16*)(ws + 4456448);  // 262144 bf16
    __bf16* VeLo = (__bf16*)(ws + 4587520);  // 262144 bf16
    float* tmpT = ws + 4718592;              // 16384 floats  (total ~18.9 MB)

    hipMemsetAsync(P, 0, 262144 * sizeof(float), stream);

    k_rt  <<<dim3(128, 2), 256, 0, stream>>>(x, U1, U3, rhsT, part);
    k_red <<<C_N, 512, 0, stream>>>(part, tmpT);
    k_prep<<<1024, 256, 0, stream>>>(Ve, VeHi, VeLo);
    k_lhs <<<dim3(V_N / 256, T_N), 256, 0, stream>>>(tmpT, U2, lhs);
    k_P   <<<dim3(8, 8, 8), 256, 0, stream>>>(rhsT, lhs, P);
    k_fused<<<dim3(8, C_N), 512, 0, stream>>>(P, be, VeHi, VeLo, out);
}

// Round 3
// 255.773 us; speedup vs baseline: 1.6373x; 1.0983x over previous
//
#include <hip/hip_runtime.h>

#define V_N 4096
#define C_N 32
#define T_N 512

typedef float f32x4 __attribute__((ext_vector_type(4)));
typedef __bf16 bf16x8 __attribute__((ext_vector_type(8)));

// ---------------------------------------------------------------------------
// Fused first pass over x (read x exactly once):
//   rhsT[v][t] = sum_c x[v,c,t]*U3[c]
//   part[chunk][c][t] = sum_{v in chunk} x[v,c,t]*U1[v]   (reduced by k_red)
__global__ __launch_bounds__(256) void k_rt(const float* __restrict__ x,
                                            const float* __restrict__ U1,
                                            const float* __restrict__ U3,
                                            float* __restrict__ rhsT,
                                            float* __restrict__ part) {
    int chunk = blockIdx.x;                 // 0..127, 32 v each
    int t = blockIdx.y * 256 + threadIdx.x; // 0..511
    float u3r[C_N];
#pragma unroll
    for (int c = 0; c < C_N; ++c) u3r[c] = U3[c];
    float accT[C_N];
#pragma unroll
    for (int c = 0; c < C_N; ++c) accT[c] = 0.f;
    int v0 = chunk * 32;
    for (int v = v0; v < v0 + 32; ++v) {
        float u1 = U1[v];
        const float* xp = x + (size_t)v * (C_N * T_N) + t;
        float u3acc = 0.f;
#pragma unroll
        for (int c = 0; c < C_N; ++c) {
            float xv = xp[c * T_N];
            u3acc = fmaf(xv, u3r[c], u3acc);
            accT[c] = fmaf(xv, u1, accT[c]);
        }
        rhsT[(size_t)v * T_N + t] = u3acc;
    }
#pragma unroll
    for (int c = 0; c < C_N; ++c)
        part[((size_t)chunk * C_N + c) * T_N + t] = accT[c];
}

// ---------------------------------------------------------------------------
// tmpT[c][t] = sum_chunk part[chunk][c][t]
__global__ __launch_bounds__(512) void k_red(const float* __restrict__ part,
                                             float* __restrict__ tmpT) {
    int c = blockIdx.x;
    int t = threadIdx.x;
    float s = 0.f;
    for (int b = 0; b < 128; ++b)
        s += part[((size_t)b * C_N + c) * T_N + t];
    tmpT[c * T_N + t] = s;
}

// ---------------------------------------------------------------------------
// Ve -> hi/lo bf16 split (hi + lo reproduces Ve to ~16 mantissa bits)
__global__ __launch_bounds__(256) void k_prep(const float* __restrict__ Ve,
                                              __bf16* __restrict__ VeHi,
                                              __bf16* __restrict__ VeLo) {
    int i = blockIdx.x * 256 + threadIdx.x;
    float v = Ve[i];
    __bf16 h = (__bf16)v;
    VeHi[i] = h;
    VeLo[i] = (__bf16)(v - (float)h);
}

// ---------------------------------------------------------------------------
// lhs[t][v2] = sum_c tmpT[c][t] * U2[c][v2]
__global__ __launch_bounds__(256) void k_lhs(const float* __restrict__ tmpT,
                                             const float* __restrict__ U2,
                                             float* __restrict__ lhs) {
    int t = blockIdx.y;
    int v2 = blockIdx.x * 256 + threadIdx.x;
    float a = 0.f;
#pragma unroll
    for (int c = 0; c < C_N; ++c)
        a = fmaf(tmpT[c * T_N + t], U2[(size_t)c * V_N + v2], a);
    lhs[(size_t)t * V_N + v2] = a;
}

// ---------------------------------------------------------------------------
// Ppart[z][s][r] = sum_{v in kslice z} rhsT[v][s] * lhs[r][v]  (fp32, no atomics)
__global__ __launch_bounds__(256) void k_P(const float* __restrict__ rhsT,
                                           const float* __restrict__ lhs,
                                           float* __restrict__ Ppart) {
    int rbase = blockIdx.x * 64, sbase = blockIdx.y * 64, kbase = blockIdx.z * 512;
    float* Pz = Ppart + (size_t)blockIdx.z * T_N * T_N;
    __shared__ float As[16][64];   // [v][s]
    __shared__ float Bs[16][65];   // [v][r] (padded)
    int tid = threadIdx.x;
    int tx = tid & 15, ty = tid >> 4;
    float acc[4][4] = {};
    for (int k0 = kbase; k0 < kbase + 512; k0 += 16) {
        for (int i = tid; i < 1024; i += 256) {
            int kk = i >> 6, ss = i & 63;
            As[kk][ss] = rhsT[(size_t)(k0 + kk) * T_N + sbase + ss];
        }
        for (int i = tid; i < 1024; i += 256) {
            int rr = i >> 4, kk = i & 15;
            Bs[kk][rr] = lhs[(size_t)(rbase + rr) * V_N + k0 + kk];
        }
        __syncthreads();
#pragma unroll
        for (int kk = 0; kk < 16; ++kk) {
            float a[4], b[4];
#pragma unroll
            for (int i = 0; i < 4; ++i) a[i] = As[kk][ty * 4 + i];
#pragma unroll
            for (int j = 0; j < 4; ++j) b[j] = Bs[kk][tx * 4 + j];
#pragma unroll
            for (int i = 0; i < 4; ++i)
#pragma unroll
                for (int j = 0; j < 4; ++j) acc[i][j] = fmaf(a[i], b[j], acc[i][j]);
        }
        __syncthreads();
    }
#pragma unroll
    for (int i = 0; i < 4; ++i)
#pragma unroll
        for (int j = 0; j < 4; ++j)
            Pz[(size_t)(sbase + ty * 4 + i) * T_N + rbase + tx * 4 + j] = acc[i][j];
}

// ---------------------------------------------------------------------------
// P[i] = sum_z Ppart[z][i]   (float4 per thread)
__global__ __launch_bounds__(256) void k_Pred(const float* __restrict__ Ppart,
                                              float* __restrict__ P) {
    int i = (blockIdx.x * 256 + threadIdx.x) * 4;
    f32x4 s = *(const f32x4*)&Ppart[i];
#pragma unroll
    for (int z = 1; z < 8; ++z)
        s += *(const f32x4*)&Ppart[(size_t)z * T_N * T_N + i];
    *(f32x4*)&P[i] = s;
}

// ---------------------------------------------------------------------------
// Fused: per block (c, 64-wide r tile), all t:
//   S[s][r] = sigmoid(P[s][r] + be[c][s][r])   (bf16, LDS, XOR-swizzled)
//   E[t][r] = sum_s (VeHi+VeLo)[t][s] * S[s][r]  via MFMA 16x16x32 bf16
//   out[c][t][r] = softmax_t(E)
// 8 waves: wave grid 4(t) x 2(r); per wave 128t x 32r = 8x2 MFMA tiles.
__global__ __launch_bounds__(512) void k_fused(const float* __restrict__ P,
                                               const float* __restrict__ be,
                                               const __bf16* __restrict__ VeHi,
                                               const __bf16* __restrict__ VeLo,
                                               float* __restrict__ out) {
    __shared__ __bf16 S[64][512];   // 64KB: S^T layout [r][s], swizzled
    const int rbase = blockIdx.x * 64;
    const int c = blockIdx.y;
    const int tid = threadIdx.x;
    const size_t cTT = (size_t)c * T_N * T_N;

    // ---- phase 1: sigmoid once per element, store S^T[r][s] bf16 swizzled
    {
        int rl = tid & 63;          // local r (column of GEMM)
        int s0 = tid >> 6;          // 0..7
        int rg = rbase + rl;
        int swz = (rl & 7) << 3;
        for (int i = 0; i < 64; ++i) {
            int s = i * 8 + s0;
            size_t off = (size_t)s * T_N + rg;
            float v = P[off] + be[cTT + off];
            float sg = 1.0f / (1.0f + __expf(-v));
            S[rl][s ^ swz] = (__bf16)sg;
        }
    }
    __syncthreads();

    const int lane = tid & 63;
    const int w = tid >> 6;     // 0..7
    const int wt = w & 3;       // t-wave: 128 rows each
    const int wr = w >> 2;      // r-wave: 32 cols each
    const int lhi = lane >> 4;  // 0..3
    const int llo = lane & 15;

    f32x4 acc[8][2];
#pragma unroll
    for (int mi = 0; mi < 8; ++mi)
#pragma unroll
        for (int ni = 0; ni < 2; ++ni) acc[mi][ni] = (f32x4)0.f;

    // ---- phase 2: K loop (s), A = Ve hi/lo from global (L2-hot), B from LDS
    for (int k0 = 0; k0 < T_N; k0 += 32) {
        bf16x8 b[2];
        int g = (k0 >> 3) + lhi;
#pragma unroll
        for (int ni = 0; ni < 2; ++ni) {
            int rr = wr * 32 + ni * 16 + llo;
            b[ni] = *(const bf16x8*)&S[rr][(g ^ (rr & 7)) << 3];
        }
#pragma unroll
        for (int mi = 0; mi < 8; ++mi) {
            int t = wt * 128 + mi * 16 + llo;
            const __bf16* pa = VeHi + (size_t)t * T_N + k0 + lhi * 8;
            const __bf16* pl = VeLo + (size_t)t * T_N + k0 + lhi * 8;
            bf16x8 ah = *(const bf16x8*)pa;
            bf16x8 al = *(const bf16x8*)pl;
#pragma unroll
            for (int ni = 0; ni < 2; ++ni) {
                acc[mi][ni] = __builtin_amdgcn_mfma_f32_16x16x32_bf16(ah, b[ni], acc[mi][ni], 0, 0, 0);
                acc[mi][ni] = __builtin_amdgcn_mfma_f32_16x16x32_bf16(al, b[ni], acc[mi][ni], 0, 0, 0);
            }
        }
    }
    __syncthreads();            // done with S; reuse as reduction buffers

    float* red = (float*)&S[0][0];  // [0..255]=max, [256..511]=sum
    float gmax[2], gsum[2];

    // ---- phase 3a: column max over t (acc row = lhi*4+q, col = llo)
#pragma unroll
    for (int ni = 0; ni < 2; ++ni) {
        float m = -3.4e38f;
#pragma unroll
        for (int mi = 0; mi < 8; ++mi)
#pragma unroll
            for (int q = 0; q < 4; ++q) m = fmaxf(m, acc[mi][ni][q]);
        m = fmaxf(m, __shfl_xor(m, 16));
        m = fmaxf(m, __shfl_xor(m, 32));
        if (lane < 16) red[wt * 64 + wr * 32 + ni * 16 + llo] = m;
    }
    __syncthreads();
#pragma unroll
    for (int ni = 0; ni < 2; ++ni) {
        int col = wr * 32 + ni * 16 + llo;
        gmax[ni] = fmaxf(fmaxf(red[col], red[64 + col]),
                         fmaxf(red[128 + col], red[192 + col]));
    }
    // ---- phase 3b: exp + column sum
#pragma unroll
    for (int ni = 0; ni < 2; ++ni) {
        float ssum = 0.f;
#pragma unroll
        for (int mi = 0; mi < 8; ++mi)
#pragma unroll
            for (int q = 0; q < 4; ++q) {
                float e = __expf(acc[mi][ni][q] - gmax[ni]);
                acc[mi][ni][q] = e;
                ssum += e;
            }
        ssum += __shfl_xor(ssum, 16);
        ssum += __shfl_xor(ssum, 32);
        if (lane < 16) red[256 + wt * 64 + wr * 32 + ni * 16 + llo] = ssum;
    }
    __syncthreads();
#pragma unroll
    for (int ni = 0; ni < 2; ++ni) {
        int col = wr * 32 + ni * 16 + llo;
        gsum[ni] = 1.0f / (red[256 + col] + red[256 + 64 + col] +
                           red[256 + 128 + col] + red[256 + 192 + col]);
    }
    // ---- phase 3c: write normalized output
#pragma unroll
    for (int mi = 0; mi < 8; ++mi)
#pragma unroll
        for (int ni = 0; ni < 2; ++ni) {
            int rg = rbase + wr * 32 + ni * 16 + llo;
#pragma unroll
            for (int q = 0; q < 4; ++q) {
                int t = wt * 128 + mi * 16 + lhi * 4 + q;
                out[cTT + (size_t)t * T_N + rg] = acc[mi][ni][q] * gsum[ni];
            }
        }
}

// ---------------------------------------------------------------------------
extern "C" void kernel_launch(void* const* d_in, const int* in_sizes, int n_in,
                              void* d_out, int out_size, void* d_ws, size_t ws_size,
                              hipStream_t stream) {
    const float* x  = (const float*)d_in[0];
    const float* U1 = (const float*)d_in[1];
    const float* U2 = (const float*)d_in[2];
    const float* U3 = (const float*)d_in[3];
    const float* be = (const float*)d_in[4];
    const float* Ve = (const float*)d_in[5];
    float* out = (float*)d_out;

    float* ws    = (float*)d_ws;
    float* rhsT  = ws;                        // 2097152 floats
    float* part  = ws + 2097152;              // 2097152 (dead after k_red)
    float* lhs   = ws + 2097152;              // overlays part
    float* Ppart = ws + 4194304;              // 8*262144 = 2097152
    float* P     = ws + 6291456;              // 262144
    __bf16* VeHi = (__bf16*)(ws + 6553600);   // 262144 bf16 (131072 floats)
    __bf16* VeLo = (__bf16*)(ws + 6684672);   // 262144 bf16
    float* tmpT  = ws + 6815744;              // 16384   (total ~27.3 MB)

    k_rt  <<<dim3(128, 2), 256, 0, stream>>>(x, U1, U3, rhsT, part);
    k_red <<<C_N, 512, 0, stream>>>(part, tmpT);
    k_prep<<<1024, 256, 0, stream>>>(Ve, VeHi, VeLo);
    k_lhs <<<dim3(V_N / 256, T_N), 256, 0, stream>>>(tmpT, U2, lhs);
    k_P   <<<dim3(8, 8, 8), 256, 0, stream>>>(rhsT, lhs, Ppart);
    k_Pred<<<256, 256, 0, stream>>>(Ppart, P);
    k_fused<<<dim3(8, C_N), 512, 0, stream>>>(P, be, VeHi, VeLo, out);
}

// Round 4
// 191.415 us; speedup vs baseline: 2.1878x; 1.3362x over previous
//
#include <hip/hip_runtime.h>

#define V_N 4096
#define C_N 32
#define T_N 512

typedef float f32x4 __attribute__((ext_vector_type(4)));
typedef __bf16 bf16x8 __attribute__((ext_vector_type(8)));

// ---------------------------------------------------------------------------
// One pass over x (read x exactly once). Per chunk of 16 v:
//   partT[chunk][c][t] = sum_{v in chunk} x[v,c,t]*U1[v]
//   partG[chunk][c][t] = sum_{v in chunk} rhs[t,v]*U2[c,v]
//     where rhs[t,v] = sum_c' x[v,c',t]*U3[c']  (held in u3acc[16] registers)
// This folds the old K=4096 GEMM P=rhs@lhs^T into the x pass via
// P[s,r] = sum_c tmp[r,c]*G[s,c].
__global__ __launch_bounds__(256) void k_rt(const float* __restrict__ x,
                                            const float* __restrict__ U1,
                                            const float* __restrict__ U2,
                                            const float* __restrict__ U3,
                                            float* __restrict__ partT,
                                            float* __restrict__ partG) {
    const int chunk = blockIdx.x;                 // 0..255, 16 v each
    const int t = blockIdx.y * 256 + threadIdx.x; // 0..511
    const int v0 = chunk * 16;
    float u3acc[16];
#pragma unroll
    for (int i = 0; i < 16; ++i) u3acc[i] = 0.f;
    const float* xbase = x + (size_t)v0 * (C_N * T_N) + t;

    for (int c = 0; c < C_N; ++c) {
        float u3 = U3[c];
        float u1acc = 0.f;
#pragma unroll
        for (int vi = 0; vi < 16; ++vi) {
            float xv = xbase[(size_t)vi * (C_N * T_N) + c * T_N];
            u1acc = fmaf(xv, U1[v0 + vi], u1acc);
            u3acc[vi] = fmaf(xv, u3, u3acc[vi]);
        }
        partT[((size_t)chunk * C_N + c) * T_N + t] = u1acc;
    }
#pragma unroll
    for (int c = 0; c < C_N; ++c) {
        float g = 0.f;
#pragma unroll
        for (int vi = 0; vi < 16; ++vi)
            g = fmaf(u3acc[vi], U2[(size_t)c * V_N + v0 + vi], g);
        partG[((size_t)chunk * C_N + c) * T_N + t] = g;
    }
}

// ---------------------------------------------------------------------------
// tmpT[c][t] = sum_chunk partT ; Gc[c][t] = sum_chunk partG
__global__ __launch_bounds__(128) void k_red(const float* __restrict__ partT,
                                             const float* __restrict__ partG,
                                             float* __restrict__ tmpT,
                                             float* __restrict__ Gc) {
    int c = blockIdx.x;                       // 0..31
    int t = blockIdx.y * 128 + threadIdx.x;   // 4 segs of 128
    float sT = 0.f, sG = 0.f;
    for (int b = 0; b < 256; ++b) {
        size_t off = ((size_t)b * C_N + c) * T_N + t;
        sT += partT[off];
        sG += partG[off];
    }
    tmpT[c * T_N + t] = sT;
    Gc[c * T_N + t] = sG;
}

// ---------------------------------------------------------------------------
// Ve -> hi/lo bf16 split (hi + lo reproduces Ve to ~16 mantissa bits)
__global__ __launch_bounds__(256) void k_prep(const float* __restrict__ Ve,
                                              __bf16* __restrict__ VeHi,
                                              __bf16* __restrict__ VeLo) {
    int i = blockIdx.x * 256 + threadIdx.x;
    float v = Ve[i];
    __bf16 h = (__bf16)v;
    VeHi[i] = h;
    VeLo[i] = (__bf16)(v - (float)h);
}

// ---------------------------------------------------------------------------
// P[s][r] = sum_c Gc[c][s] * tmpT[c][r]    (K=32 tiny GEMM, fp32)
__global__ __launch_bounds__(256) void k_P2(const float* __restrict__ Gc,
                                            const float* __restrict__ tmpT,
                                            float* __restrict__ P) {
    __shared__ float Gs[32][64];
    __shared__ float Ts[32][64];
    int rbase = blockIdx.x * 64, sbase = blockIdx.y * 64;
    int tid = threadIdx.x;
    int tx = tid & 15, ty = tid >> 4;
    for (int i = tid; i < 2048; i += 256) {
        int cc = i >> 6, j = i & 63;
        Gs[cc][j] = Gc[cc * T_N + sbase + j];
        Ts[cc][j] = tmpT[cc * T_N + rbase + j];
    }
    __syncthreads();
    float acc[4][4] = {};
#pragma unroll
    for (int cc = 0; cc < 32; ++cc) {
        float a[4], b[4];
#pragma unroll
        for (int i = 0; i < 4; ++i) a[i] = Gs[cc][ty * 4 + i];
#pragma unroll
        for (int j = 0; j < 4; ++j) b[j] = Ts[cc][tx * 4 + j];
#pragma unroll
        for (int i = 0; i < 4; ++i)
#pragma unroll
            for (int j = 0; j < 4; ++j) acc[i][j] = fmaf(a[i], b[j], acc[i][j]);
    }
#pragma unroll
    for (int i = 0; i < 4; ++i) {
        f32x4 vv = {acc[i][0], acc[i][1], acc[i][2], acc[i][3]};
        *(f32x4*)&P[(size_t)(sbase + ty * 4 + i) * T_N + rbase + tx * 4] = vv;
    }
}

// ---------------------------------------------------------------------------
// Fused: per block (c, 64-wide r tile), all t:
//   S[s][r] = sigmoid(P[s][r] + be[c][s][r])   (bf16, LDS, XOR-swizzled)
//   E[t][r] = sum_s (VeHi+VeLo)[t][s] * S[s][r]  via MFMA 16x16x32 bf16
//   out[c][t][r] = softmax_t(E)
// 8 waves: wave grid 4(t) x 2(r); per wave 128t x 32r = 8x2 MFMA tiles.
__global__ __launch_bounds__(512) void k_fused(const float* __restrict__ P,
                                               const float* __restrict__ be,
                                               const __bf16* __restrict__ VeHi,
                                               const __bf16* __restrict__ VeLo,
                                               float* __restrict__ out) {
    __shared__ __bf16 S[64][512];   // 64KB: S^T layout [r][s], swizzled
    const int rbase = blockIdx.x * 64;
    const int c = blockIdx.y;
    const int tid = threadIdx.x;
    const size_t cTT = (size_t)c * T_N * T_N;

    // ---- phase 1: sigmoid once per element, store S^T[r][s] bf16 swizzled
    {
        int rl = tid & 63;          // local r (column of GEMM)
        int s0 = tid >> 6;          // 0..7
        int rg = rbase + rl;
        int swz = (rl & 7) << 3;
        for (int i = 0; i < 64; ++i) {
            int s = i * 8 + s0;
            size_t off = (size_t)s * T_N + rg;
            float v = P[off] + be[cTT + off];
            float sg = 1.0f / (1.0f + __expf(-v));
            S[rl][s ^ swz] = (__bf16)sg;
        }
    }
    __syncthreads();

    const int lane = tid & 63;
    const int w = tid >> 6;     // 0..7
    const int wt = w & 3;       // t-wave: 128 rows each
    const int wr = w >> 2;      // r-wave: 32 cols each
    const int lhi = lane >> 4;  // 0..3
    const int llo = lane & 15;

    f32x4 acc[8][2];
#pragma unroll
    for (int mi = 0; mi < 8; ++mi)
#pragma unroll
        for (int ni = 0; ni < 2; ++ni) acc[mi][ni] = (f32x4)0.f;

    // ---- phase 2: K loop (s), A = Ve hi/lo from global (L2-hot), B from LDS
    for (int k0 = 0; k0 < T_N; k0 += 32) {
        bf16x8 b[2];
        int g = (k0 >> 3) + lhi;
#pragma unroll
        for (int ni = 0; ni < 2; ++ni) {
            int rr = wr * 32 + ni * 16 + llo;
            b[ni] = *(const bf16x8*)&S[rr][(g ^ (rr & 7)) << 3];
        }
#pragma unroll
        for (int mi = 0; mi < 8; ++mi) {
            int t = wt * 128 + mi * 16 + llo;
            const __bf16* pa = VeHi + (size_t)t * T_N + k0 + lhi * 8;
            const __bf16* pl = VeLo + (size_t)t * T_N + k0 + lhi * 8;
            bf16x8 ah = *(const bf16x8*)pa;
            bf16x8 al = *(const bf16x8*)pl;
#pragma unroll
            for (int ni = 0; ni < 2; ++ni) {
                acc[mi][ni] = __builtin_amdgcn_mfma_f32_16x16x32_bf16(ah, b[ni], acc[mi][ni], 0, 0, 0);
                acc[mi][ni] = __builtin_amdgcn_mfma_f32_16x16x32_bf16(al, b[ni], acc[mi][ni], 0, 0, 0);
            }
        }
    }
    __syncthreads();            // done with S; reuse as reduction buffers

    float* red = (float*)&S[0][0];  // [0..255]=max, [256..511]=sum
    float gmax[2], gsum[2];

    // ---- phase 3a: column max over t (acc row = lhi*4+q, col = llo)
#pragma unroll
    for (int ni = 0; ni < 2; ++ni) {
        float m = -3.4e38f;
#pragma unroll
        for (int mi = 0; mi < 8; ++mi)
#pragma unroll
            for (int q = 0; q < 4; ++q) m = fmaxf(m, acc[mi][ni][q]);
        m = fmaxf(m, __shfl_xor(m, 16));
        m = fmaxf(m, __shfl_xor(m, 32));
        if (lane < 16) red[wt * 64 + wr * 32 + ni * 16 + llo] = m;
    }
    __syncthreads();
#pragma unroll
    for (int ni = 0; ni < 2; ++ni) {
        int col = wr * 32 + ni * 16 + llo;
        gmax[ni] = fmaxf(fmaxf(red[col], red[64 + col]),
                         fmaxf(red[128 + col], red[192 + col]));
    }
    // ---- phase 3b: exp + column sum
#pragma unroll
    for (int ni = 0; ni < 2; ++ni) {
        float ssum = 0.f;
#pragma unroll
        for (int mi = 0; mi < 8; ++mi)
#pragma unroll
            for (int q = 0; q < 4; ++q) {
                float e = __expf(acc[mi][ni][q] - gmax[ni]);
                acc[mi][ni][q] = e;
                ssum += e;
            }
        ssum += __shfl_xor(ssum, 16);
        ssum += __shfl_xor(ssum, 32);
        if (lane < 16) red[256 + wt * 64 + wr * 32 + ni * 16 + llo] = ssum;
    }
    __syncthreads();
#pragma unroll
    for (int ni = 0; ni < 2; ++ni) {
        int col = wr * 32 + ni * 16 + llo;
        gsum[ni] = 1.0f / (red[256 + col] + red[256 + 64 + col] +
                           red[256 + 128 + col] + red[256 + 192 + col]);
    }
    // ---- phase 3c: write normalized output
#pragma unroll
    for (int mi = 0; mi < 8; ++mi)
#pragma unroll
        for (int ni = 0; ni < 2; ++ni) {
            int rg = rbase + wr * 32 + ni * 16 + llo;
#pragma unroll
            for (int q = 0; q < 4; ++q) {
                int t = wt * 128 + mi * 16 + lhi * 4 + q;
                out[cTT + (size_t)t * T_N + rg] = acc[mi][ni][q] * gsum[ni];
            }
        }
}

// ---------------------------------------------------------------------------
extern "C" void kernel_launch(void* const* d_in, const int* in_sizes, int n_in,
                              void* d_out, int out_size, void* d_ws, size_t ws_size,
                              hipStream_t stream) {
    const float* x  = (const float*)d_in[0];
    const float* U1 = (const float*)d_in[1];
    const float* U2 = (const float*)d_in[2];
    const float* U3 = (const float*)d_in[3];
    const float* be = (const float*)d_in[4];
    const float* Ve = (const float*)d_in[5];
    float* out = (float*)d_out;

    float* ws    = (float*)d_ws;
    float* partT = ws;                        // 256*32*512 = 4194304 floats
    float* partG = ws + 4194304;              // 4194304
    float* P     = ws + 8388608;              // 262144
    float* Gc    = ws + 8650752;              // 16384
    float* tmpT  = ws + 8667136;              // 16384
    __bf16* VeHi = (__bf16*)(ws + 8683520);   // 262144 bf16 (131072 float slots)
    __bf16* VeLo = (__bf16*)(ws + 8814592);   // 262144 bf16
    // total ~8945664 floats ~= 35.8 MB

    k_rt  <<<dim3(256, 2), 256, 0, stream>>>(x, U1, U2, U3, partT, partG);
    k_red <<<dim3(C_N, 4), 128, 0, stream>>>(partT, partG, tmpT, Gc);
    k_prep<<<1024, 256, 0, stream>>>(Ve, VeHi, VeLo);
    k_P2  <<<dim3(8, 8), 256, 0, stream>>>(Gc, tmpT, P);
    k_fused<<<dim3(8, C_N), 512, 0, stream>>>(P, be, VeHi, VeLo, out);
}

// Round 5
// 175.832 us; speedup vs baseline: 2.3816x; 1.0886x over previous
//
#include <hip/hip_runtime.h>

#define V_N 4096
#define C_N 32
#define T_N 512

typedef float f32x2 __attribute__((ext_vector_type(2)));
typedef float f32x4 __attribute__((ext_vector_type(4)));
typedef __bf16 bf16x8 __attribute__((ext_vector_type(8)));

// ---------------------------------------------------------------------------
// One pass over x (read x exactly once), vec2 loads. Per chunk of 16 v:
//   partT[chunk][c][t] = sum_{v in chunk} x[v,c,t]*U1[v]
//   partG[chunk][c][t] = sum_{v in chunk} rhs[t,v]*U2[c,v]
//     rhs[t,v] = sum_c' x[v,c',t]*U3[c']  (held in f32x2 rhs[16] registers)
__global__ __launch_bounds__(256) void k_rt(const float* __restrict__ x,
                                            const float* __restrict__ U1,
                                            const float* __restrict__ U2,
                                            const float* __restrict__ U3,
                                            float* __restrict__ partT,
                                            float* __restrict__ partG) {
    const int chunk = blockIdx.x;     // 0..255, 16 v each
    const int t = threadIdx.x * 2;    // vec2 over t
    const int v0 = chunk * 16;
    f32x2 rhs[16];
#pragma unroll
    for (int i = 0; i < 16; ++i) rhs[i] = (f32x2)0.f;
    const float* xbase = x + (size_t)v0 * (C_N * T_N) + t;

    for (int c = 0; c < C_N; ++c) {
        float u3 = U3[c];
        f32x2 u1acc = (f32x2)0.f;
#pragma unroll
        for (int vi = 0; vi < 16; ++vi) {
            f32x2 xv = *(const f32x2*)(xbase + (size_t)vi * (C_N * T_N) + c * T_N);
            float u1 = U1[v0 + vi];
            u1acc.x = fmaf(xv.x, u1, u1acc.x);
            u1acc.y = fmaf(xv.y, u1, u1acc.y);
            rhs[vi].x = fmaf(xv.x, u3, rhs[vi].x);
            rhs[vi].y = fmaf(xv.y, u3, rhs[vi].y);
        }
        *(f32x2*)&partT[((size_t)chunk * C_N + c) * T_N + t] = u1acc;
    }
#pragma unroll
    for (int c = 0; c < C_N; ++c) {
        f32x2 g = (f32x2)0.f;
#pragma unroll
        for (int vi = 0; vi < 16; ++vi) {
            float u2 = U2[(size_t)c * V_N + v0 + vi];
            g.x = fmaf(rhs[vi].x, u2, g.x);
            g.y = fmaf(rhs[vi].y, u2, g.y);
        }
        *(f32x2*)&partG[((size_t)chunk * C_N + c) * T_N + t] = g;
    }
}

// ---------------------------------------------------------------------------
// Level-1 reduce: 8 b-segments of 32 chunks each, f32x4.
__global__ __launch_bounds__(128) void k_red1(const float* __restrict__ partT,
                                              const float* __restrict__ partG,
                                              float* __restrict__ p2T,
                                              float* __restrict__ p2G) {
    int c = blockIdx.x, bs = blockIdx.y;   // 32 x 8
    int t4 = threadIdx.x * 4;
    f32x4 sT = (f32x4)0.f, sG = (f32x4)0.f;
    for (int b = bs * 32; b < bs * 32 + 32; ++b) {
        size_t off = ((size_t)b * C_N + c) * T_N + t4;
        sT += *(const f32x4*)&partT[off];
        sG += *(const f32x4*)&partG[off];
    }
    size_t o2 = ((size_t)bs * C_N + c) * T_N + t4;
    *(f32x4*)&p2T[o2] = sT;
    *(f32x4*)&p2G[o2] = sG;
}

// ---------------------------------------------------------------------------
// Aux: blocks 0..31 = level-2 reduce; blocks 32.. = Ve hi/lo split packed in
// MFMA A-fragment order: frag index o -> tile=(t/16)*16+(k/32), lane, elem:
//   t = (tile>>4)*16 + (lane&15),  k = (tile&15)*32 + (lane>>4)*8 + (o&7)
__global__ __launch_bounds__(128) void k_aux(const float* __restrict__ p2T,
                                             const float* __restrict__ p2G,
                                             float* __restrict__ tmpT,
                                             float* __restrict__ Gc,
                                             const float* __restrict__ Ve,
                                             __bf16* __restrict__ VeHi,
                                             __bf16* __restrict__ VeLo) {
    int bid = blockIdx.x;
    if (bid < 32) {
        int c = bid;
        int t4 = threadIdx.x * 4;
        f32x4 sT = (f32x4)0.f, sG = (f32x4)0.f;
#pragma unroll
        for (int bs = 0; bs < 8; ++bs) {
            size_t off = ((size_t)bs * C_N + c) * T_N + t4;
            sT += *(const f32x4*)&p2T[off];
            sG += *(const f32x4*)&p2G[off];
        }
        *(f32x4*)&tmpT[c * T_N + t4] = sT;
        *(f32x4*)&Gc[c * T_N + t4] = sG;
    } else {
        int o = (bid - 32) * 128 + threadIdx.x;   // 0..262143
        int e = o & 7, l = (o >> 3) & 63, tile = o >> 9;
        int kk = tile & 15, tt = tile >> 4;
        int t = tt * 16 + (l & 15);
        int k = kk * 32 + (l >> 4) * 8 + e;
        float v = Ve[(size_t)t * T_N + k];
        __bf16 h = (__bf16)v;
        VeHi[o] = h;
        VeLo[o] = (__bf16)(v - (float)h);
    }
}

// ---------------------------------------------------------------------------
// P[s][r] = sum_c Gc[c][s] * tmpT[c][r]    (K=32 tiny GEMM, fp32)
__global__ __launch_bounds__(256) void k_P2(const float* __restrict__ Gc,
                                            const float* __restrict__ tmpT,
                                            float* __restrict__ P) {
    __shared__ float Gs[32][64];
    __shared__ float Ts[32][64];
    int rbase = blockIdx.x * 64, sbase = blockIdx.y * 64;
    int tid = threadIdx.x;
    int tx = tid & 15, ty = tid >> 4;
    for (int i = tid; i < 2048; i += 256) {
        int cc = i >> 6, j = i & 63;
        Gs[cc][j] = Gc[cc * T_N + sbase + j];
        Ts[cc][j] = tmpT[cc * T_N + rbase + j];
    }
    __syncthreads();
    float acc[4][4] = {};
#pragma unroll
    for (int cc = 0; cc < 32; ++cc) {
        float a[4], b[4];
#pragma unroll
        for (int i = 0; i < 4; ++i) a[i] = Gs[cc][ty * 4 + i];
#pragma unroll
        for (int j = 0; j < 4; ++j) b[j] = Ts[cc][tx * 4 + j];
#pragma unroll
        for (int i = 0; i < 4; ++i)
#pragma unroll
            for (int j = 0; j < 4; ++j) acc[i][j] = fmaf(a[i], b[j], acc[i][j]);
    }
#pragma unroll
    for (int i = 0; i < 4; ++i) {
        f32x4 vv = {acc[i][0], acc[i][1], acc[i][2], acc[i][3]};
        *(f32x4*)&P[(size_t)(sbase + ty * 4 + i) * T_N + rbase + tx * 4] = vv;
    }
}

// ---------------------------------------------------------------------------
// Fused: per block (c, 64-wide r tile), all t:
//   S[s][r] = sigmoid(P[s][r] + be[c][s][r])   (bf16, LDS, XOR-swizzled)
//   E[t][r] = sum_s (VeHi+VeLo)[t][s] * S[s][r]  via MFMA 16x16x32 bf16
//   out[c][t][r] = softmax_t(E)
// 8 waves: wave grid 4(t) x 2(r); per wave 128t x 32r = 8x2 MFMA tiles.
// A operands come from fragment-packed VeHi/VeLo (1KB contiguous per wave).
__global__ __launch_bounds__(512) void k_fused(const float* __restrict__ P,
                                               const float* __restrict__ be,
                                               const __bf16* __restrict__ VeHi,
                                               const __bf16* __restrict__ VeLo,
                                               float* __restrict__ out) {
    __shared__ __bf16 S[64][512];   // 64KB: S^T layout [r][s], swizzled
    const int rbase = blockIdx.x * 64;
    const int c = blockIdx.y;
    const int tid = threadIdx.x;
    const size_t cTT = (size_t)c * T_N * T_N;

    // ---- phase 1: sigmoid once per element (f32x4 loads), S^T bf16 swizzled
    {
        int r4 = (tid & 15) * 4;
        int s0 = tid >> 4;          // 0..31
        for (int i = 0; i < 16; ++i) {
            int s = i * 32 + s0;
            size_t off = (size_t)s * T_N + rbase + r4;
            f32x4 pv = *(const f32x4*)&P[off];
            f32x4 bv = *(const f32x4*)&be[cTT + off];
#pragma unroll
            for (int j = 0; j < 4; ++j) {
                float vv = pv[j] + bv[j];
                float sg = 1.0f / (1.0f + __expf(-vv));
                int rl = r4 + j;
                S[rl][s ^ ((rl & 7) << 3)] = (__bf16)sg;
            }
        }
    }
    __syncthreads();

    const int lane = tid & 63;
    const int w = tid >> 6;     // 0..7
    const int wt = w & 3;       // t-wave: 128 rows each
    const int wr = w >> 2;      // r-wave: 32 cols each
    const int lhi = lane >> 4;  // 0..3
    const int llo = lane & 15;

    const bf16x8* fragHi = (const bf16x8*)VeHi;
    const bf16x8* fragLo = (const bf16x8*)VeLo;

    f32x4 acc[8][2];
#pragma unroll
    for (int mi = 0; mi < 8; ++mi)
#pragma unroll
        for (int ni = 0; ni < 2; ++ni) acc[mi][ni] = (f32x4)0.f;

    // ---- phase 2: K loop (s), A = packed Ve frags (L2-hot), B from LDS
    for (int k0 = 0; k0 < T_N; k0 += 32) {
        bf16x8 b[2];
        int g = (k0 >> 3) + lhi;
#pragma unroll
        for (int ni = 0; ni < 2; ++ni) {
            int rr = wr * 32 + ni * 16 + llo;
            b[ni] = *(const bf16x8*)&S[rr][(g ^ (rr & 7)) << 3];
        }
#pragma unroll
        for (int mi = 0; mi < 8; ++mi) {
            int tile = (wt * 8 + mi) * 16 + (k0 >> 5);
            bf16x8 ah = fragHi[tile * 64 + lane];
            bf16x8 al = fragLo[tile * 64 + lane];
#pragma unroll
            for (int ni = 0; ni < 2; ++ni) {
                acc[mi][ni] = __builtin_amdgcn_mfma_f32_16x16x32_bf16(ah, b[ni], acc[mi][ni], 0, 0, 0);
                acc[mi][ni] = __builtin_amdgcn_mfma_f32_16x16x32_bf16(al, b[ni], acc[mi][ni], 0, 0, 0);
            }
        }
    }
    __syncthreads();            // done with S; reuse as reduction buffers

    float* red = (float*)&S[0][0];  // [0..255]=max, [256..511]=sum
    float gmax[2], gsum[2];

    // ---- phase 3a: column max over t (acc row = lhi*4+q, col = llo)
#pragma unroll
    for (int ni = 0; ni < 2; ++ni) {
        float m = -3.4e38f;
#pragma unroll
        for (int mi = 0; mi < 8; ++mi)
#pragma unroll
            for (int q = 0; q < 4; ++q) m = fmaxf(m, acc[mi][ni][q]);
        m = fmaxf(m, __shfl_xor(m, 16));
        m = fmaxf(m, __shfl_xor(m, 32));
        if (lane < 16) red[wt * 64 + wr * 32 + ni * 16 + llo] = m;
    }
    __syncthreads();
#pragma unroll
    for (int ni = 0; ni < 2; ++ni) {
        int col = wr * 32 + ni * 16 + llo;
        gmax[ni] = fmaxf(fmaxf(red[col], red[64 + col]),
                         fmaxf(red[128 + col], red[192 + col]));
    }
    // ---- phase 3b: exp + column sum
#pragma unroll
    for (int ni = 0; ni < 2; ++ni) {
        float ssum = 0.f;
#pragma unroll
        for (int mi = 0; mi < 8; ++mi)
#pragma unroll
            for (int q = 0; q < 4; ++q) {
                float e = __expf(acc[mi][ni][q] - gmax[ni]);
                acc[mi][ni][q] = e;
                ssum += e;
            }
        ssum += __shfl_xor(ssum, 16);
        ssum += __shfl_xor(ssum, 32);
        if (lane < 16) red[256 + wt * 64 + wr * 32 + ni * 16 + llo] = ssum;
    }
    __syncthreads();
#pragma unroll
    for (int ni = 0; ni < 2; ++ni) {
        int col = wr * 32 + ni * 16 + llo;
        gsum[ni] = 1.0f / (red[256 + col] + red[256 + 64 + col] +
                           red[256 + 128 + col] + red[256 + 192 + col]);
    }
    // ---- phase 3c: write normalized output
#pragma unroll
    for (int mi = 0; mi < 8; ++mi)
#pragma unroll
        for (int ni = 0; ni < 2; ++ni) {
            int rg = rbase + wr * 32 + ni * 16 + llo;
#pragma unroll
            for (int q = 0; q < 4; ++q) {
                int t = wt * 128 + mi * 16 + lhi * 4 + q;
                out[cTT + (size_t)t * T_N + rg] = acc[mi][ni][q] * gsum[ni];
            }
        }
}

// ---------------------------------------------------------------------------
extern "C" void kernel_launch(void* const* d_in, const int* in_sizes, int n_in,
                              void* d_out, int out_size, void* d_ws, size_t ws_size,
                              hipStream_t stream) {
    const float* x  = (const float*)d_in[0];
    const float* U1 = (const float*)d_in[1];
    const float* U2 = (const float*)d_in[2];
    const float* U3 = (const float*)d_in[3];
    const float* be = (const float*)d_in[4];
    const float* Ve = (const float*)d_in[5];
    float* out = (float*)d_out;

    float* ws    = (float*)d_ws;
    float* partT = ws;                        // 256*32*512 = 4194304 floats
    float* partG = ws + 4194304;              // 4194304
    float* p2T   = ws + 8388608;              // 8*32*512 = 131072
    float* p2G   = ws + 8519680;              // 131072
    float* P     = ws + 8650752;              // 262144
    float* Gc    = ws + 8912896;              // 16384
    float* tmpT  = ws + 8929280;              // 16384
    __bf16* VeHi = (__bf16*)(ws + 8945664);   // 262144 bf16 (131072 slots)
    __bf16* VeLo = (__bf16*)(ws + 9076736);   // 262144 bf16
    // total 9207808 floats ~= 36.8 MB

    k_rt  <<<256, 256, 0, stream>>>(x, U1, U2, U3, partT, partG);
    k_red1<<<dim3(C_N, 8), 128, 0, stream>>>(partT, partG, p2T, p2G);
    k_aux <<<32 + 2048, 128, 0, stream>>>(p2T, p2G, tmpT, Gc, Ve, VeHi, VeLo);
    k_P2  <<<dim3(8, 8), 256, 0, stream>>>(Gc, tmpT, P);
    k_fused<<<dim3(8, C_N), 512, 0, stream>>>(P, be, VeHi, VeLo, out);
}

// Round 6
// 165.211 us; speedup vs baseline: 2.5348x; 1.0643x over previous
//
#include <hip/hip_runtime.h>

#define V_N 4096
#define C_N 32
#define T_N 512

typedef float f32x2 __attribute__((ext_vector_type(2)));
typedef float f32x4 __attribute__((ext_vector_type(4)));
typedef __bf16 bf16x8 __attribute__((ext_vector_type(8)));

// ---------------------------------------------------------------------------
// Pre-pass: blocks 0..31 zero tmpT+Gc (adjacent, 32768 floats); blocks 32..
// split Ve into hi/lo bf16 packed in MFMA A-fragment order:
//   o -> tile=(t/16)*16+(k/32), lane l, elem e:
//   t = (tile>>4)*16 + (l&15),  k = (tile&15)*32 + (l>>4)*8 + e
__global__ __launch_bounds__(256) void k_pre(float* __restrict__ zz,
                                             const float* __restrict__ Ve,
                                             __bf16* __restrict__ VeHi,
                                             __bf16* __restrict__ VeLo) {
    int bid = blockIdx.x;
    if (bid < 32) {
        int i = (bid * 256 + threadIdx.x) * 4;
        *(f32x4*)&zz[i] = (f32x4)0.f;
    } else {
        int o = (bid - 32) * 256 + threadIdx.x;   // 0..262143
        int e = o & 7, l = (o >> 3) & 63, tile = o >> 9;
        int kk = tile & 15, tt = tile >> 4;
        int t = tt * 16 + (l & 15);
        int k = kk * 32 + (l >> 4) * 8 + e;
        float v = Ve[(size_t)t * T_N + k];
        __bf16 h = (__bf16)v;
        VeHi[o] = h;
        VeLo[o] = (__bf16)(v - (float)h);
    }
}

// ---------------------------------------------------------------------------
// One pass over x (read x exactly once), vec2 loads. Per chunk of 16 v:
//   tmpT[c][t] += sum_{v in chunk} x[v,c,t]*U1[v]        (L2-resident atomics)
//   Gc[c][t]   += sum_{v in chunk} rhs[t,v]*U2[c,v]
//     rhs[t,v] = sum_c' x[v,c',t]*U3[c']  (held in f32x2 rhs[16] registers)
__global__ __launch_bounds__(256) void k_rt(const float* __restrict__ x,
                                            const float* __restrict__ U1,
                                            const float* __restrict__ U2,
                                            const float* __restrict__ U3,
                                            float* __restrict__ tmpT,
                                            float* __restrict__ Gc) {
    const int chunk = blockIdx.x;     // 0..255, 16 v each
    const int t = threadIdx.x * 2;    // vec2 over t
    const int v0 = chunk * 16;
    f32x2 rhs[16];
#pragma unroll
    for (int i = 0; i < 16; ++i) rhs[i] = (f32x2)0.f;
    const float* xbase = x + (size_t)v0 * (C_N * T_N) + t;

    for (int c = 0; c < C_N; ++c) {
        float u3 = U3[c];
        f32x2 u1acc = (f32x2)0.f;
#pragma unroll
        for (int vi = 0; vi < 16; ++vi) {
            f32x2 xv = *(const f32x2*)(xbase + (size_t)vi * (C_N * T_N) + c * T_N);
            float u1 = U1[v0 + vi];
            u1acc.x = fmaf(xv.x, u1, u1acc.x);
            u1acc.y = fmaf(xv.y, u1, u1acc.y);
            rhs[vi].x = fmaf(xv.x, u3, rhs[vi].x);
            rhs[vi].y = fmaf(xv.y, u3, rhs[vi].y);
        }
        atomicAdd(&tmpT[c * T_N + t], u1acc.x);
        atomicAdd(&tmpT[c * T_N + t + 1], u1acc.y);
    }
#pragma unroll
    for (int c = 0; c < C_N; ++c) {
        f32x2 g = (f32x2)0.f;
#pragma unroll
        for (int vi = 0; vi < 16; ++vi) {
            float u2 = U2[(size_t)c * V_N + v0 + vi];
            g.x = fmaf(rhs[vi].x, u2, g.x);
            g.y = fmaf(rhs[vi].y, u2, g.y);
        }
        atomicAdd(&Gc[c * T_N + t], g.x);
        atomicAdd(&Gc[c * T_N + t + 1], g.y);
    }
}

// ---------------------------------------------------------------------------
// P[s][r] = sum_c Gc[c][s] * tmpT[c][r]    (K=32 tiny GEMM, fp32)
__global__ __launch_bounds__(256) void k_P2(const float* __restrict__ Gc,
                                            const float* __restrict__ tmpT,
                                            float* __restrict__ P) {
    __shared__ float Gs[32][64];
    __shared__ float Ts[32][64];
    int rbase = blockIdx.x * 64, sbase = blockIdx.y * 64;
    int tid = threadIdx.x;
    int tx = tid & 15, ty = tid >> 4;
    for (int i = tid; i < 2048; i += 256) {
        int cc = i >> 6, j = i & 63;
        Gs[cc][j] = Gc[cc * T_N + sbase + j];
        Ts[cc][j] = tmpT[cc * T_N + rbase + j];
    }
    __syncthreads();
    float acc[4][4] = {};
#pragma unroll
    for (int cc = 0; cc < 32; ++cc) {
        float a[4], b[4];
#pragma unroll
        for (int i = 0; i < 4; ++i) a[i] = Gs[cc][ty * 4 + i];
#pragma unroll
        for (int j = 0; j < 4; ++j) b[j] = Ts[cc][tx * 4 + j];
#pragma unroll
        for (int i = 0; i < 4; ++i)
#pragma unroll
            for (int j = 0; j < 4; ++j) acc[i][j] = fmaf(a[i], b[j], acc[i][j]);
    }
#pragma unroll
    for (int i = 0; i < 4; ++i) {
        f32x4 vv = {acc[i][0], acc[i][1], acc[i][2], acc[i][3]};
        *(f32x4*)&P[(size_t)(sbase + ty * 4 + i) * T_N + rbase + tx * 4] = vv;
    }
}

// ---------------------------------------------------------------------------
// Fused: per block (c, 32-wide r tile), all t (512 blocks -> 2 blocks/CU so
// sigmoid/HBM phases of one block overlap MFMA/L2 phases of the other):
//   S[s][r] = sigmoid(P[s][r] + be[c][s][r])   (bf16, LDS 32KB, XOR-swizzled)
//   E[t][r] = sum_s (VeHi+VeLo)[t][s] * S[s][r]  via MFMA 16x16x32 bf16
//   out[c][t][r] = softmax_t(E)
// 8 waves = 4(t) x 2(r); per wave 128t x 16r = 8x1 tiles, acc = 32 VGPR.
__global__ __launch_bounds__(512, 4) void k_fused(const float* __restrict__ P,
                                                  const float* __restrict__ be,
                                                  const __bf16* __restrict__ VeHi,
                                                  const __bf16* __restrict__ VeLo,
                                                  float* __restrict__ out) {
    __shared__ __bf16 S[32][512];   // 32KB: S^T layout [r][s], swizzled
    const int rbase = blockIdx.x * 32;
    const int c = blockIdx.y;
    const int tid = threadIdx.x;
    const size_t cTT = (size_t)c * T_N * T_N;

    // ---- phase 1: sigmoid once per element (f32x4 loads), S^T bf16 swizzled
    {
        int r4 = (tid & 7) * 4;
        int s0 = tid >> 3;          // 0..63
        for (int i = 0; i < 8; ++i) {
            int s = i * 64 + s0;
            size_t off = (size_t)s * T_N + rbase + r4;
            f32x4 pv = *(const f32x4*)&P[off];
            f32x4 bv = *(const f32x4*)&be[cTT + off];
#pragma unroll
            for (int j = 0; j < 4; ++j) {
                float vv = pv[j] + bv[j];
                float sg = 1.0f / (1.0f + __expf(-vv));
                int rl = r4 + j;
                S[rl][s ^ ((rl & 7) << 3)] = (__bf16)sg;
            }
        }
    }
    __syncthreads();

    const int lane = tid & 63;
    const int w = tid >> 6;     // 0..7
    const int wt = w & 3;       // t-wave: 128 rows each
    const int wr = w >> 2;      // r-wave: 16 cols each
    const int lhi = lane >> 4;  // 0..3
    const int llo = lane & 15;

    const bf16x8* fragHi = (const bf16x8*)VeHi;
    const bf16x8* fragLo = (const bf16x8*)VeLo;

    f32x4 acc[8];
#pragma unroll
    for (int mi = 0; mi < 8; ++mi) acc[mi] = (f32x4)0.f;

    // ---- phase 2: K loop (s), A = packed Ve frags (L2-hot), B from LDS
    for (int k0 = 0; k0 < T_N; k0 += 32) {
        int rr = wr * 16 + llo;
        int g = (k0 >> 3) + lhi;
        bf16x8 b = *(const bf16x8*)&S[rr][(g ^ (rr & 7)) << 3];
#pragma unroll
        for (int mi = 0; mi < 8; ++mi) {
            int tile = (wt * 8 + mi) * 16 + (k0 >> 5);
            bf16x8 ah = fragHi[tile * 64 + lane];
            bf16x8 al = fragLo[tile * 64 + lane];
            acc[mi] = __builtin_amdgcn_mfma_f32_16x16x32_bf16(ah, b, acc[mi], 0, 0, 0);
            acc[mi] = __builtin_amdgcn_mfma_f32_16x16x32_bf16(al, b, acc[mi], 0, 0, 0);
        }
    }
    __syncthreads();            // done with S; reuse as reduction buffers

    float* red = (float*)&S[0][0];  // [0..127]=max, [128..255]=sum
    float gmax, gsum;

    // ---- phase 3a: column max over t (acc row = lhi*4+q, col = llo)
    {
        float m = -3.4e38f;
#pragma unroll
        for (int mi = 0; mi < 8; ++mi)
#pragma unroll
            for (int q = 0; q < 4; ++q) m = fmaxf(m, acc[mi][q]);
        m = fmaxf(m, __shfl_xor(m, 16));
        m = fmaxf(m, __shfl_xor(m, 32));
        if (lane < 16) red[wt * 32 + wr * 16 + llo] = m;
    }
    __syncthreads();
    {
        int col = wr * 16 + llo;
        gmax = fmaxf(fmaxf(red[col], red[32 + col]),
                     fmaxf(red[64 + col], red[96 + col]));
    }
    // ---- phase 3b: exp + column sum
    {
        float ssum = 0.f;
#pragma unroll
        for (int mi = 0; mi < 8; ++mi)
#pragma unroll
            for (int q = 0; q < 4; ++q) {
                float e = __expf(acc[mi][q] - gmax);
                acc[mi][q] = e;
                ssum += e;
            }
        ssum += __shfl_xor(ssum, 16);
        ssum += __shfl_xor(ssum, 32);
        if (lane < 16) red[128 + wt * 32 + wr * 16 + llo] = ssum;
    }
    __syncthreads();
    {
        int col = wr * 16 + llo;
        gsum = 1.0f / (red[128 + col] + red[128 + 32 + col] +
                       red[128 + 64 + col] + red[128 + 96 + col]);
    }
    // ---- phase 3c: write normalized output
    {
        int rg = rbase + wr * 16 + llo;
#pragma unroll
        for (int mi = 0; mi < 8; ++mi)
#pragma unroll
            for (int q = 0; q < 4; ++q) {
                int t = wt * 128 + mi * 16 + lhi * 4 + q;
                out[cTT + (size_t)t * T_N + rg] = acc[mi][q] * gsum;
            }
    }
}

// ---------------------------------------------------------------------------
extern "C" void kernel_launch(void* const* d_in, const int* in_sizes, int n_in,
                              void* d_out, int out_size, void* d_ws, size_t ws_size,
                              hipStream_t stream) {
    const float* x  = (const float*)d_in[0];
    const float* U1 = (const float*)d_in[1];
    const float* U2 = (const float*)d_in[2];
    const float* U3 = (const float*)d_in[3];
    const float* be = (const float*)d_in[4];
    const float* Ve = (const float*)d_in[5];
    float* out = (float*)d_out;

    float* ws    = (float*)d_ws;
    float* tmpT  = ws;                        // 16384 floats
    float* Gc    = ws + 16384;                // 16384 (adjacent: zeroed together)
    float* P     = ws + 32768;                // 262144
    __bf16* VeHi = (__bf16*)(ws + 294912);    // 262144 bf16 (131072 slots)
    __bf16* VeLo = (__bf16*)(ws + 425984);    // 262144 bf16
    // total 557056 floats ~= 2.2 MB

    k_pre <<<32 + 1024, 256, 0, stream>>>(ws, Ve, VeHi, VeLo);
    k_rt  <<<256, 256, 0, stream>>>(x, U1, U2, U3, tmpT, Gc);
    k_P2  <<<dim3(8, 8), 256, 0, stream>>>(Gc, tmpT, P);
    k_fused<<<dim3(16, C_N), 512, 0, stream>>>(P, be, VeHi, VeLo, out);
}

// Round 8
// 155.991 us; speedup vs baseline: 2.6846x; 1.0591x over previous
//
#include <hip/hip_runtime.h>

#define V_N 4096
#define C_N 32
#define T_N 512

typedef float f32x2 __attribute__((ext_vector_type(2)));
typedef float f32x4 __attribute__((ext_vector_type(4)));
typedef __bf16 bf16x8 __attribute__((ext_vector_type(8)));

__device__ inline f32x2 fma2(f32x2 a, float b, f32x2 c) {
    f32x2 r;
    r.x = fmaf(a.x, b, c.x); r.y = fmaf(a.y, b, c.y);
    return r;
}

// ---------------------------------------------------------------------------
// Pre-pass: split Ve into hi/lo bf16 packed in MFMA A-fragment order:
//   o -> tile=(t/16)*16+(k/32), lane l, elem e:
//   t = (tile>>4)*16 + (l&15),  k = (tile&15)*32 + (l>>4)*8 + e
__global__ __launch_bounds__(256) void k_pre(const float* __restrict__ Ve,
                                             __bf16* __restrict__ VeHi,
                                             __bf16* __restrict__ VeLo) {
    int o = blockIdx.x * 256 + threadIdx.x;   // 0..262143
    int e = o & 7, l = (o >> 3) & 63, tile = o >> 9;
    int kk = tile & 15, tt = tile >> 4;
    int t = tt * 16 + (l & 15);
    int k = kk * 32 + (l >> 4) * 8 + e;
    float v = Ve[(size_t)t * T_N + k];
    __bf16 h = (__bf16)v;
    VeHi[o] = h;
    VeLo[o] = (__bf16)(v - (float)h);
}

// ---------------------------------------------------------------------------
// Streaming x-pass (read x exactly once; no LDS, no atomics).
// Block = one 8-v chunk; 256 threads, thread owns f32x2 over full 512 t.
//   partT[vc][c][t] = sum_{vi} x[v0+vi,c,t]*U1[v0+vi]
//   partG[vc][c][t] = sum_{vi} rhs[vi,t]*U2[c,v0+vi],
//     rhs[vi,t] = sum_c x[v0+vi,c,t]*U3[c]   (f32x2 x 8 in registers)
__global__ __launch_bounds__(256, 2) void k_rt(const float* __restrict__ x,
                                               const float* __restrict__ U1,
                                               const float* __restrict__ U2,
                                               const float* __restrict__ U3,
                                               float* __restrict__ partT,
                                               float* __restrict__ partG) {
    const int vc = blockIdx.x;        // 0..511
    const int t2 = threadIdx.x;       // 0..255 -> t = t2*2, t2*2+1
    const int v0 = vc * 8;
    const float* xb = x + (size_t)v0 * (C_N * T_N) + t2 * 2;
    float u1r[8];
#pragma unroll
    for (int vi = 0; vi < 8; ++vi) u1r[vi] = U1[v0 + vi];
    f32x2 rhs[8];
#pragma unroll
    for (int vi = 0; vi < 8; ++vi) rhs[vi] = (f32x2)0.f;

    const size_t pbase = ((size_t)vc * C_N) * T_N + t2 * 2;
#pragma unroll 2
    for (int c = 0; c < C_N; ++c) {
        float u3 = U3[c];
        f32x2 u1a = (f32x2)0.f;
#pragma unroll
        for (int vi = 0; vi < 8; ++vi) {
            f32x2 xv = *(const f32x2*)(xb + (size_t)vi * (C_N * T_N) + c * T_N);
            u1a = fma2(xv, u1r[vi], u1a);
            rhs[vi] = fma2(xv, u3, rhs[vi]);
        }
        *(f32x2*)&partT[pbase + (size_t)c * T_N] = u1a;
    }
#pragma unroll 4
    for (int c = 0; c < C_N; ++c) {
        f32x2 g = (f32x2)0.f;
#pragma unroll
        for (int vi = 0; vi < 8; ++vi)
            g = fma2(rhs[vi], U2[(size_t)c * V_N + v0 + vi], g);
        *(f32x2*)&partG[pbase + (size_t)c * T_N] = g;
    }
}

// ---------------------------------------------------------------------------
// Fixed-order reduce of 512 chunk-partials -> tmpT[32][512], Gc[32][512].
// 8192 f32x4 outputs (T:0..4095, G:4096..8191); 8 threads per output
// (64-chunk segments each) + LDS combine. Deterministic.
__global__ __launch_bounds__(128) void k_red(const float* __restrict__ partT,
                                             const float* __restrict__ partG,
                                             float* __restrict__ tmpT,
                                             float* __restrict__ Gc) {
    __shared__ f32x4 red[16][8];
    int oid = threadIdx.x >> 3;               // 0..15
    int seg = threadIdx.x & 7;                // 0..7
    int o = blockIdx.x * 16 + oid;            // 0..8191
    int isG = o >> 12;
    int oo = o & 4095;                        // f32x4 slot in [32][128]
    int c = oo >> 7;
    int tq = oo & 127;                        // t = tq*4
    const float* src = isG ? partG : partT;
    size_t base = (size_t)c * T_N + tq * 4;
    f32x4 s = (f32x4)0.f;
#pragma unroll 4
    for (int vc = seg * 64; vc < seg * 64 + 64; ++vc)
        s += *(const f32x4*)&src[base + (size_t)vc * (C_N * T_N)];
    red[oid][seg] = s;
    __syncthreads();
    if (seg == 0) {
        f32x4 tot = red[oid][0];
#pragma unroll
        for (int k = 1; k < 8; ++k) tot += red[oid][k];
        float* dst = isG ? Gc : tmpT;
        *(f32x4*)&dst[c * T_N + tq * 4] = tot;
    }
}

// ---------------------------------------------------------------------------
// P[s][r] = sum_c Gc[c][s] * tmpT[c][r]    (K=32 tiny GEMM, fp32)
__global__ __launch_bounds__(256) void k_P2(const float* __restrict__ Gc,
                                            const float* __restrict__ tmpT,
                                            float* __restrict__ P) {
    __shared__ float Gs[32][64];
    __shared__ float Ts[32][64];
    int rbase = blockIdx.x * 64, sbase = blockIdx.y * 64;
    int tid = threadIdx.x;
    int tx = tid & 15, ty = tid >> 4;
    for (int i = tid; i < 2048; i += 256) {
        int cc = i >> 6, j = i & 63;
        Gs[cc][j] = Gc[cc * T_N + sbase + j];
        Ts[cc][j] = tmpT[cc * T_N + rbase + j];
    }
    __syncthreads();
    float acc[4][4] = {};
#pragma unroll
    for (int cc = 0; cc < 32; ++cc) {
        float a[4], b[4];
#pragma unroll
        for (int i = 0; i < 4; ++i) a[i] = Gs[cc][ty * 4 + i];
#pragma unroll
        for (int j = 0; j < 4; ++j) b[j] = Ts[cc][tx * 4 + j];
#pragma unroll
        for (int i = 0; i < 4; ++i)
#pragma unroll
            for (int j = 0; j < 4; ++j) acc[i][j] = fmaf(a[i], b[j], acc[i][j]);
    }
#pragma unroll
    for (int i = 0; i < 4; ++i) {
        f32x4 vv = {acc[i][0], acc[i][1], acc[i][2], acc[i][3]};
        *(f32x4*)&P[(size_t)(sbase + ty * 4 + i) * T_N + rbase + tx * 4] = vv;
    }
}

// ---------------------------------------------------------------------------
// Fused: per block (c, 32-wide r tile), all t (512 blocks, 2 blocks/CU):
//   S[s][r] = sigmoid(P[s][r] + be[c][s][r])   (bf16, LDS 32KB, XOR-swizzled)
//   E[t][r] = sum_s (VeHi+VeLo)[t][s] * S[s][r]  via MFMA 16x16x32 bf16
//   out[c][t][r] = softmax_t(E)
// 8 waves = 4(t) x 2(r); per wave 128t x 16r = 8x1 tiles.
__global__ __launch_bounds__(512, 4) void k_fused(const float* __restrict__ P,
                                                  const float* __restrict__ be,
                                                  const __bf16* __restrict__ VeHi,
                                                  const __bf16* __restrict__ VeLo,
                                                  float* __restrict__ out) {
    __shared__ __bf16 S[32][512];   // 32KB: S^T layout [r][s], swizzled
    const int rbase = blockIdx.x * 32;
    const int c = blockIdx.y;
    const int tid = threadIdx.x;
    const size_t cTT = (size_t)c * T_N * T_N;

    // ---- phase 1: sigmoid once per element (f32x4 loads), S^T bf16 swizzled
    {
        int r4 = (tid & 7) * 4;
        int s0 = tid >> 3;          // 0..63
        for (int i = 0; i < 8; ++i) {
            int s = i * 64 + s0;
            size_t off = (size_t)s * T_N + rbase + r4;
            f32x4 pv = *(const f32x4*)&P[off];
            f32x4 bv = *(const f32x4*)&be[cTT + off];
#pragma unroll
            for (int j = 0; j < 4; ++j) {
                float vv = pv[j] + bv[j];
                float sg = 1.0f / (1.0f + __expf(-vv));
                int rl = r4 + j;
                S[rl][s ^ ((rl & 7) << 3)] = (__bf16)sg;
            }
        }
    }
    __syncthreads();

    const int lane = tid & 63;
    const int w = tid >> 6;     // 0..7
    const int wt = w & 3;       // t-wave: 128 rows each
    const int wr = w >> 2;      // r-wave: 16 cols each
    const int lhi = lane >> 4;  // 0..3
    const int llo = lane & 15;

    const bf16x8* fragHi = (const bf16x8*)VeHi;
    const bf16x8* fragLo = (const bf16x8*)VeLo;

    f32x4 acc[8];
#pragma unroll
    for (int mi = 0; mi < 8; ++mi) acc[mi] = (f32x4)0.f;

    // ---- phase 2: K loop (s), A = packed Ve frags (L2-hot), B from LDS
    for (int k0 = 0; k0 < T_N; k0 += 32) {
        int rr = wr * 16 + llo;
        int g = (k0 >> 3) + lhi;
        bf16x8 b = *(const bf16x8*)&S[rr][(g ^ (rr & 7)) << 3];
#pragma unroll
        for (int mi = 0; mi < 8; ++mi) {
            int tile = (wt * 8 + mi) * 16 + (k0 >> 5);
            bf16x8 ah = fragHi[tile * 64 + lane];
            bf16x8 al = fragLo[tile * 64 + lane];
            acc[mi] = __builtin_amdgcn_mfma_f32_16x16x32_bf16(ah, b, acc[mi], 0, 0, 0);
            acc[mi] = __builtin_amdgcn_mfma_f32_16x16x32_bf16(al, b, acc[mi], 0, 0, 0);
        }
    }
    __syncthreads();            // done with S; reuse as reduction buffers

    float* red = (float*)&S[0][0];  // [0..127]=max, [128..255]=sum
    float gmax, gsum;

    // ---- phase 3a: column max over t
    {
        float m = -3.4e38f;
#pragma unroll
        for (int mi = 0; mi < 8; ++mi)
#pragma unroll
            for (int q = 0; q < 4; ++q) m = fmaxf(m, acc[mi][q]);
        m = fmaxf(m, __shfl_xor(m, 16));
        m = fmaxf(m, __shfl_xor(m, 32));
        if (lane < 16) red[wt * 32 + wr * 16 + llo] = m;
    }
    __syncthreads();
    {
        int col = wr * 16 + llo;
        gmax = fmaxf(fmaxf(red[col], red[32 + col]),
                     fmaxf(red[64 + col], red[96 + col]));
    }
    // ---- phase 3b: exp + column sum
    {
        float ssum = 0.f;
#pragma unroll
        for (int mi = 0; mi < 8; ++mi)
#pragma unroll
            for (int q = 0; q < 4; ++q) {
                float e = __expf(acc[mi][q] - gmax);
                acc[mi][q] = e;
                ssum += e;
            }
        ssum += __shfl_xor(ssum, 16);
        ssum += __shfl_xor(ssum, 32);
        if (lane < 16) red[128 + wt * 32 + wr * 16 + llo] = ssum;
    }
    __syncthreads();
    {
        int col = wr * 16 + llo;
        gsum = 1.0f / (red[128 + col] + red[128 + 32 + col] +
                       red[128 + 64 + col] + red[128 + 96 + col]);
    }
    // ---- phase 3c: write normalized output
    {
        int rg = rbase + wr * 16 + llo;
#pragma unroll
        for (int mi = 0; mi < 8; ++mi)
#pragma unroll
            for (int q = 0; q < 4; ++q) {
                int t = wt * 128 + mi * 16 + lhi * 4 + q;
                out[cTT + (size_t)t * T_N + rg] = acc[mi][q] * gsum;
            }
    }
}

// ---------------------------------------------------------------------------
extern "C" void kernel_launch(void* const* d_in, const int* in_sizes, int n_in,
                              void* d_out, int out_size, void* d_ws, size_t ws_size,
                              hipStream_t stream) {
    const float* x  = (const float*)d_in[0];
    const float* U1 = (const float*)d_in[1];
    const float* U2 = (const float*)d_in[2];
    const float* U3 = (const float*)d_in[3];
    const float* be = (const float*)d_in[4];
    const float* Ve = (const float*)d_in[5];
    float* out = (float*)d_out;

    float* ws    = (float*)d_ws;
    float* partT = ws;                        // 512*32*512 = 8388608 floats
    float* partG = ws + 8388608;              // 8388608
    float* P     = ws + 16777216;             // 262144
    __bf16* VeHi = (__bf16*)(ws + 17039360);  // 262144 bf16 (131072 slots)
    __bf16* VeLo = (__bf16*)(ws + 17170432);  // 262144 bf16
    float* tmpT  = ws + 17301504;             // 16384
    float* Gc    = ws + 17317888;             // 16384
    // total ~17334272 floats ~= 69.3 MB

    k_pre <<<1024, 256, 0, stream>>>(Ve, VeHi, VeLo);
    k_rt  <<<512, 256, 0, stream>>>(x, U1, U2, U3, partT, partG);
    k_red <<<512, 128, 0, stream>>>(partT, partG, tmpT, Gc);
    k_P2  <<<dim3(8, 8), 256, 0, stream>>>(Gc, tmpT, P);
    k_fused<<<dim3(16, C_N), 512, 0, stream>>>(P, be, VeHi, VeLo, out);
}